// Round 12
// baseline (124.307 us; speedup 1.0000x reference)
//
#include <hip/hip_runtime.h>
#include <hip/hip_bf16.h>

// FourierKANLayer: y[n,o] = sum_{i,g} cos(x[n,i]*(g+1))*C[0,o,i,g]
//                         + sin(x[n,i]*(g+1))*C[1,o,i,g] + bias[o]
// N=8192, I=512, O=512, G=8  ->  GEMM [N x K]*[K x O], K = I*16 = 8192
// Round 12: 4 blocks/CU. BM=64, BN=256, BK=32, 4 waves (wave-tile 32x128),
// KSPLIT=4, grid 1024. LDS 40KB/block (A 2x4KB + B 2x16KB pair-row 8-slot
// XOR). TLP was the only lever that ever moved this kernel (R1->R2 +45%);
// per-SIMD accounting shows ~1900 cyc/kt-pair of unhidden stall at 2 waves.

typedef __attribute__((ext_vector_type(8)))  short s16x8;
typedef __attribute__((ext_vector_type(4)))  int   i32x4;
typedef __attribute__((ext_vector_type(4)))  float f32x4;
typedef __attribute__((ext_vector_type(16))) float f32x16;

#define NROWS 8192
#define IDIM  512
#define ODIM  512
#define KDIM  8192   // IDIM*16

static __device__ __forceinline__ short f2bf(float f) {
    union { float f; unsigned u; } v; v.f = f;
    unsigned r = v.u + 0x7fffu + ((v.u >> 16) & 1u);  // RNE
    return (short)(r >> 16);
}

static __device__ __forceinline__ float bf2f(short h) {
    union { unsigned u; float f; } v;
    v.u = ((unsigned)(unsigned short)h) << 16;
    return v.f;
}

static __device__ __forceinline__ int pkbf(float c, float s) {
    union { __hip_bfloat162 h; int i; } u;
    u.h = __float22bfloat162_rn(make_float2(c, s));   // low = cos, high = sin
    return u.i;
}

// ---- prep: coeffs [2][O][I][G] f32  ->  Wb[O][K] bf16, k = i*16 + 2g + t ----
__global__ __launch_bounds__(256) void fkan_prep(const float* __restrict__ cf,
                                                 short* __restrict__ Wb) {
    const int o = blockIdx.x;
    const int tid = threadIdx.x;
#pragma unroll
    for (int rep = 0; rep < 2; ++rep) {
        const int i = tid + rep * 256;
        const float* c0 = cf + (o * 512 + i) * 8;            // t=0
        const float* c1 = cf + ((512 + o) * 512 + i) * 8;    // t=1
        float4 a0 = *(const float4*)c0;
        float4 a1 = *(const float4*)(c0 + 4);
        float4 b0 = *(const float4*)c1;
        float4 b1 = *(const float4*)(c1 + 4);
        s16x8 lo, hi;
        lo[0] = f2bf(a0.x); lo[1] = f2bf(b0.x);
        lo[2] = f2bf(a0.y); lo[3] = f2bf(b0.y);
        lo[4] = f2bf(a0.z); lo[5] = f2bf(b0.z);
        lo[6] = f2bf(a0.w); lo[7] = f2bf(b0.w);
        hi[0] = f2bf(a1.x); hi[1] = f2bf(b1.x);
        hi[2] = f2bf(a1.y); hi[3] = f2bf(b1.y);
        hi[4] = f2bf(a1.z); hi[5] = f2bf(b1.z);
        hi[6] = f2bf(a1.w); hi[7] = f2bf(b1.w);
        *(s16x8*)(Wb + o * KDIM + i * 16)     = lo;
        *(s16x8*)(Wb + o * KDIM + i * 16 + 8) = hi;
    }
}

// ---- main GEMM: BM=64, BN=256, BK=32, 256 threads (4 waves, wave 32x128) ----
// grid 1024 (128 bm x 2 bn x 4 kc), 4 blocks/CU. 32x32x16 MFMA.
// LDS pair-row: line l (128B, 8 slots) holds rows {2l,2l+1}; logical chunk
// cb = (row&1)*4 + kchunk stored at slot cb ^ (l&7) (rule-21 pre-swizzled).
__global__ __launch_bounds__(256, 4) void fkan_gemm12(const float* __restrict__ x,
                                                      const short* __restrict__ Wb,
                                                      short* __restrict__ P) {
    __shared__ short As[2][64 * 32];    // 4KB/buf  (64 n-rows x 32 k)
    __shared__ short Bs[2][256 * 32];   // 16KB/buf (256 o-rows x 32 k)

    const int bid = blockIdx.x;
    const int xcd = bid & 7;
    const int bn = xcd & 1, kc = xcd >> 1;          // 8 (bn,kc) combos -> 8 XCDs
    const int bm = bid >> 3;                        // [0,128)
    const int n0 = bm * 64, o0 = bn * 256, i0 = kc * 128;
    const int kbase = i0 * 16;
    const int NKT = 64;                             // 128 i / 2 i-per-kt

    const int tid = threadIdx.x;
    const int wid = tid >> 6, lane = tid & 63;
    const int l32 = lane & 31, hi32 = lane >> 5;
    const int wr = wid >> 1, wc = wid & 1;          // wave-tile 32 x 128

    f32x16 acc[4];                                  // [nt], 64 f32
#pragma unroll
    for (int b = 0; b < 4; ++b)
#pragma unroll
        for (int e = 0; e < 16; ++e) acc[b][e] = 0.f;

    // ---- A stager: even threads only; element e = tid>>1 -> row e>>1, i-sel e&1
    const bool stg = (tid & 1) == 0;
    const int srow = tid >> 2;                      // 0..63
    const int sisel = (tid >> 1) & 1;
    const float* xsrc = x + (size_t)(n0 + srow) * 512 + i0 + sisel;
    const int slin = srow >> 1;
    const int scb0 = (srow & 1) * 4 + sisel * 2;
    const int sAo0 = slin * 64 + ((scb0 ^ (slin & 7))) * 8;
    const int sAo1 = slin * 64 + (((scb0 + 1) ^ (slin & 7))) * 8;

    // ---- B gload per-thread source chunks (constant row/chunk, step 64B/kt)
    const short* bsrc[4];
#pragma unroll
    for (int w = 0; w < 4; ++w) {
        const int ch = w * 256 + tid;               // physical chunk index
        const int l = ch >> 3, sl = ch & 7;
        const int cb = sl ^ (l & 7);
        const int r = 2 * l + (cb >> 2);            // o-row
        bsrc[w] = Wb + (size_t)(o0 + r) * KDIM + kbase + (cb & 3) * 8;
    }

    // ---- frag-read offsets (shorts), kt-invariant
    const int arow = wr * 32 + l32;
    const int alin = arow >> 1;
    int aoff[2];
#pragma unroll
    for (int ks = 0; ks < 2; ++ks)
        aoff[ks] = alin * 64 + ((((arow & 1) << 2) + ks * 2 + hi32) ^ (alin & 7)) * 8;
    const int brow = wc * 128 + l32;
    const int blin = brow >> 1;
    int boff[2];
#pragma unroll
    for (int ks = 0; ks < 2; ++ks)
        boff[ks] = blin * 64 + ((((brow & 1) << 2) + ks * 2 + hi32) ^ (blin & 7)) * 8;
    // bfr[nt][ks] lives at boff[ks] + nt*1024 (nt*16 lines; XOR term invariant)

    auto stage = [&](int t, int nb, float xx) {
#pragma unroll
        for (int w = 0; w < 4; ++w) {
            short* ldst = &Bs[nb][w * 2048 + wid * 512];  // wave-uniform base
            __builtin_amdgcn_global_load_lds(
                (const __attribute__((address_space(1))) void*)(bsrc[w] + t * 32),
                (__attribute__((address_space(3))) void*)ldst, 16, 0, 0);
        }
        if (stg) {
            float s1, c1;
            __sincosf(xx, &s1, &c1);
            float c = c1, s = s1;
            i32x4 lo, hi;
#pragma unroll
            for (int g = 0; g < 8; ++g) {
                const int p = pkbf(c, s);
                if (g < 4) lo[g] = p; else hi[g - 4] = p;
                const float t1 = s * s1, t2 = c * s1;
                const float cn = __builtin_fmaf(c, c1, -t1);
                s = __builtin_fmaf(s, c1, t2);
                c = cn;
            }
            *(i32x4*)&As[nb][sAo0] = lo;
            *(i32x4*)&As[nb][sAo1] = hi;
        }
    };

    float xv = xsrc[0];                 // kt = 0
    stage(0, 0, xv);
    xv = xsrc[2];                       // kt = 1
    __syncthreads();

#pragma unroll 2
    for (int kt = 0; kt < NKT; ++kt) {
        const int cur = kt & 1;

        // ---- ks=0 fragments (A both halves + B ks0)
        s16x8 af0 = *(const s16x8*)&As[cur][aoff[0]];
        s16x8 af1 = *(const s16x8*)&As[cur][aoff[1]];
        s16x8 b0[4];
#pragma unroll
        for (int nt = 0; nt < 4; ++nt)
            b0[nt] = *(const s16x8*)&Bs[cur][boff[0] + nt * 1024];

        // ---- stage next tile (overlaps with MFMA below)
        if (kt + 1 < NKT) {
            stage(kt + 1, cur ^ 1, xv);
            if (kt + 2 < NKT) xv = xsrc[(kt + 2) * 2];
        }

#pragma unroll
        for (int nt = 0; nt < 4; ++nt)
            acc[nt] = __builtin_amdgcn_mfma_f32_32x32x16_bf16(af0, b0[nt], acc[nt], 0, 0, 0);

        // ---- ks=1
        s16x8 b1[4];
#pragma unroll
        for (int nt = 0; nt < 4; ++nt)
            b1[nt] = *(const s16x8*)&Bs[cur][boff[1] + nt * 1024];
#pragma unroll
        for (int nt = 0; nt < 4; ++nt)
            acc[nt] = __builtin_amdgcn_mfma_f32_32x32x16_bf16(af1, b1[nt], acc[nt], 0, 0, 0);

        __syncthreads();
    }

    // ---- epilogue: bf16 partial. 32x32 D layout: col = lane&31,
    //      row = (reg&3) + 8*(reg>>2) + 4*(lane>>5)   [m74/m101]
    unsigned short* dst = (unsigned short*)P + (size_t)kc * (NROWS * ODIM);
#pragma unroll
    for (int nt = 0; nt < 4; ++nt) {
        const f32x16 v = acc[nt];
        const int oc = o0 + wc * 128 + nt * 32 + l32;
        const int rb = n0 + wr * 32 + 4 * hi32;
#pragma unroll
        for (int reg = 0; reg < 16; ++reg) {
            const int row = rb + (reg & 3) + 8 * (reg >> 2);
            dst[(size_t)row * 512 + oc] = (unsigned short)f2bf(v[reg]);
        }
    }
}

// ---- combine: out = sum_{q<4} f32(Pq) + bias ----
__global__ __launch_bounds__(256) void fkan_combine4(const short* __restrict__ P,
                                                     const float* __restrict__ bias,
                                                     float* __restrict__ out) {
    const int total = NROWS * ODIM;
    const int stride = gridDim.x * 256 * 8;
    for (int e = (blockIdx.x * 256 + threadIdx.x) * 8; e < total; e += stride) {
        s16x8 a = *(const s16x8*)(P + e);
        s16x8 b = *(const s16x8*)(P + total + e);
        s16x8 c = *(const s16x8*)(P + 2 * total + e);
        s16x8 d = *(const s16x8*)(P + 3 * total + e);
        const int col = e & 511;
        float4 c0 = *(const float4*)(bias + col);
        float4 c1 = *(const float4*)(bias + col + 4);
        float4 r0, r1;
        r0.x = (bf2f(a[0]) + bf2f(b[0])) + (bf2f(c[0]) + bf2f(d[0])) + c0.x;
        r0.y = (bf2f(a[1]) + bf2f(b[1])) + (bf2f(c[1]) + bf2f(d[1])) + c0.y;
        r0.z = (bf2f(a[2]) + bf2f(b[2])) + (bf2f(c[2]) + bf2f(d[2])) + c0.z;
        r0.w = (bf2f(a[3]) + bf2f(b[3])) + (bf2f(c[3]) + bf2f(d[3])) + c0.w;
        r1.x = (bf2f(a[4]) + bf2f(b[4])) + (bf2f(c[4]) + bf2f(d[4])) + c1.x;
        r1.y = (bf2f(a[5]) + bf2f(b[5])) + (bf2f(c[5]) + bf2f(d[5])) + c1.y;
        r1.z = (bf2f(a[6]) + bf2f(b[6])) + (bf2f(c[6]) + bf2f(d[6])) + c1.z;
        r1.w = (bf2f(a[7]) + bf2f(b[7])) + (bf2f(c[7]) + bf2f(d[7])) + c1.w;
        *(float4*)(out + e)     = r0;
        *(float4*)(out + e + 4) = r1;
    }
}

// ---- fallback (small ws): KSPLIT=1 structure, grid 256, f32 out + bias ----
__global__ __launch_bounds__(256, 2) void fkan_gemm_fb(const float* __restrict__ x,
                                                       const short* __restrict__ Wb,
                                                       const float* __restrict__ bias,
                                                       float* __restrict__ outp) {
    __shared__ short As[2][128 * 64];
    __shared__ short Bs[2][128 * 64];
    const int bid = blockIdx.x;
    const int xcd = bid & 7, idx = bid >> 3;
    const int bn = xcd & 3, bm = idx + (xcd >> 2) * 32;
    const int n0 = bm * 128, o0 = bn * 128;
    const int tid = threadIdx.x;
    const int wid = tid >> 6, lane = tid & 63;
    const int lrow = lane & 15, lk = lane >> 4;
    const int wr = wid >> 1, wc = wid & 1;
    f32x4 acc[4][4];
#pragma unroll
    for (int a = 0; a < 4; ++a)
#pragma unroll
        for (int b = 0; b < 4; ++b) { f32x4 z = {0,0,0,0}; acc[a][b] = z; }
    const int nl = tid >> 1, isel = tid & 1;
    const float* xrow = x + (n0 + nl) * 512 + isel * 2;
    auto stage = [&](int t, int nb, float2 xvv) {
#pragma unroll
        for (int w = 0; w < 4; ++w) {
            const int chunk = w * 256 + tid;
            const int r = chunk >> 3, pc = chunk & 7;
            const int lc = pc ^ (r & 7);
            const short* src = Wb + (o0 + r) * KDIM + t * 64 + lc * 8;
            short* ldst = &Bs[nb][w * 2048 + wid * 512];
            __builtin_amdgcn_global_load_lds(
                (const __attribute__((address_space(1))) void*)src,
                (__attribute__((address_space(3))) void*)ldst, 16, 0, 0);
        }
#pragma unroll
        for (int ii = 0; ii < 2; ++ii) {
            const float xx = ii ? xvv.y : xvv.x;
            float s1, c1; __sincosf(xx, &s1, &c1);
            float c = c1, s = s1;
            i32x4 lo, hi;
#pragma unroll
            for (int g = 0; g < 8; ++g) {
                const int p = pkbf(c, s);
                if (g < 4) lo[g] = p; else hi[g - 4] = p;
                const float t1 = s * s1, t2 = c * s1;
                const float cn = __builtin_fmaf(c, c1, -t1);
                s = __builtin_fmaf(s, c1, t2); c = cn;
            }
            const int cb0 = (isel * 2 + ii) * 2;
            *(i32x4*)&As[nb][nl * 64 + ((cb0 ^ (nl & 7))) * 8]       = lo;
            *(i32x4*)&As[nb][nl * 64 + (((cb0 + 1) ^ (nl & 7))) * 8] = hi;
        }
    };
    float2 xv = *(const float2*)xrow;
    stage(0, 0, xv);
    xv = *(const float2*)(xrow + 4);
    __syncthreads();
    for (int kt = 0; kt < 128; ++kt) {
        const int cur = kt & 1;
        s16x8 af[2][4], bfr[2][4];
#pragma unroll
        for (int ksub = 0; ksub < 2; ++ksub) {
#pragma unroll
            for (int mf = 0; mf < 4; ++mf) {
                const int row = wr * 64 + mf * 16 + lrow;
                af[ksub][mf] = *(const s16x8*)&As[cur][row * 64 + ((ksub * 4 + lk) ^ (row & 7)) * 8];
            }
#pragma unroll
            for (int nf = 0; nf < 4; ++nf) {
                const int row = wc * 64 + nf * 16 + lrow;
                bfr[ksub][nf] = *(const s16x8*)&Bs[cur][row * 64 + ((ksub * 4 + lk) ^ (row & 7)) * 8];
            }
        }
        if (kt + 1 < 128) {
            stage(kt + 1, cur ^ 1, xv);
            if (kt + 2 < 128) xv = *(const float2*)(xrow + (kt + 2) * 4);
        }
#pragma unroll
        for (int ksub = 0; ksub < 2; ++ksub)
#pragma unroll
            for (int mf = 0; mf < 4; ++mf)
#pragma unroll
                for (int nf = 0; nf < 4; ++nf)
                    acc[mf][nf] = __builtin_amdgcn_mfma_f32_16x16x32_bf16(
                        af[ksub][mf], bfr[ksub][nf], acc[mf][nf], 0, 0, 0);
        __syncthreads();
    }
#pragma unroll
    for (int nf = 0; nf < 4; ++nf) {
        const int oc = o0 + wc * 64 + nf * 16 + lrow;
        const float bv = bias[oc];
#pragma unroll
        for (int mf = 0; mf < 4; ++mf) {
            const f32x4 v = acc[mf][nf];
            const int rbase = n0 + wr * 64 + mf * 16 + lk * 4;
#pragma unroll
            for (int j = 0; j < 4; ++j)
                outp[(size_t)(rbase + j) * 512 + oc] = v[j] + bv;
        }
    }
}

extern "C" void kernel_launch(void* const* d_in, const int* in_sizes, int n_in,
                              void* d_out, int out_size, void* d_ws, size_t ws_size,
                              hipStream_t stream) {
    const float* x    = (const float*)d_in[0];
    const float* cf   = (const float*)d_in[1];
    const float* bias = (const float*)d_in[2];
    float* out = (float*)d_out;

    const size_t partial_bytes = (size_t)4 * NROWS * ODIM * 2;   // 33.6 MB (bf16 x4)
    const size_t wb_bytes = (size_t)ODIM * KDIM * 2;             // 8.4 MB

    if (ws_size >= partial_bytes + wb_bytes) {
        short* P  = (short*)d_ws;
        short* Wb = (short*)((char*)d_ws + partial_bytes);
        fkan_prep<<<512, 256, 0, stream>>>(cf, Wb);
        fkan_gemm12<<<1024, 256, 0, stream>>>(x, Wb, P);
        fkan_combine4<<<2048, 256, 0, stream>>>(P, bias, out);
    } else {
        short* Wb = (short*)d_ws;
        fkan_prep<<<512, 256, 0, stream>>>(cf, Wb);
        fkan_gemm_fb<<<256, 256, 0, stream>>>(x, Wb, bias, out);
    }
}

// Round 13
// 97.031 us; speedup vs baseline: 1.2811x; 1.2811x over previous
//
#include <hip/hip_runtime.h>
#include <hip/hip_bf16.h>

// FourierKANLayer: y[n,o] = sum_{i,g} cos(x[n,i]*(g+1))*C[0,o,i,g]
//                         + sin(x[n,i]*(g+1))*C[1,o,i,g] + bias[o]
// N=8192, I=512, O=512, G=8  ->  GEMM [N x K]*[K x O], K = I*16 = 8192
// Round 13: R10 gemm (best: 81.3us; BM=128,BN=256,BK=32, 4 waves 2x2,
// KSPLIT=4, grid 512 = 2 blocks/CU, 32x32x16 MFMA) with the A tile moved
// back to R9's conflict-free 80B-padded layout (R10's pair-row A added
// +2.1M bank-conflict cycles; B pair-row 8-slot XOR stays, its 4.19M
// baseline is ~4% of wall and benign).

typedef __attribute__((ext_vector_type(8)))  short s16x8;
typedef __attribute__((ext_vector_type(4)))  int   i32x4;
typedef __attribute__((ext_vector_type(4)))  float f32x4;
typedef __attribute__((ext_vector_type(16))) float f32x16;

#define NROWS 8192
#define IDIM  512
#define ODIM  512
#define KDIM  8192   // IDIM*16

static __device__ __forceinline__ short f2bf(float f) {
    union { float f; unsigned u; } v; v.f = f;
    unsigned r = v.u + 0x7fffu + ((v.u >> 16) & 1u);  // RNE
    return (short)(r >> 16);
}

static __device__ __forceinline__ float bf2f(short h) {
    union { unsigned u; float f; } v;
    v.u = ((unsigned)(unsigned short)h) << 16;
    return v.f;
}

static __device__ __forceinline__ int pkbf(float c, float s) {
    union { __hip_bfloat162 h; int i; } u;
    u.h = __float22bfloat162_rn(make_float2(c, s));   // low = cos, high = sin
    return u.i;
}

// ---- prep: coeffs [2][O][I][G] f32  ->  Wb[O][K] bf16, k = i*16 + 2g + t ----
__global__ __launch_bounds__(256) void fkan_prep(const float* __restrict__ cf,
                                                 short* __restrict__ Wb) {
    const int o = blockIdx.x;
    const int tid = threadIdx.x;
#pragma unroll
    for (int rep = 0; rep < 2; ++rep) {
        const int i = tid + rep * 256;
        const float* c0 = cf + (o * 512 + i) * 8;            // t=0
        const float* c1 = cf + ((512 + o) * 512 + i) * 8;    // t=1
        float4 a0 = *(const float4*)c0;
        float4 a1 = *(const float4*)(c0 + 4);
        float4 b0 = *(const float4*)c1;
        float4 b1 = *(const float4*)(c1 + 4);
        s16x8 lo, hi;
        lo[0] = f2bf(a0.x); lo[1] = f2bf(b0.x);
        lo[2] = f2bf(a0.y); lo[3] = f2bf(b0.y);
        lo[4] = f2bf(a0.z); lo[5] = f2bf(b0.z);
        lo[6] = f2bf(a0.w); lo[7] = f2bf(b0.w);
        hi[0] = f2bf(a1.x); hi[1] = f2bf(b1.x);
        hi[2] = f2bf(a1.y); hi[3] = f2bf(b1.y);
        hi[4] = f2bf(a1.z); hi[5] = f2bf(b1.z);
        hi[6] = f2bf(a1.w); hi[7] = f2bf(b1.w);
        *(s16x8*)(Wb + o * KDIM + i * 16)     = lo;
        *(s16x8*)(Wb + o * KDIM + i * 16 + 8) = hi;
    }
}

// ---- main GEMM: BM=128, BN=256, BK=32, 256 threads (4 waves, 2x2) ----
// grid 512 (64 bm x 2 bn x 4 kc), 2 blocks/CU. 32x32x16 MFMA.
__global__ __launch_bounds__(256, 2) void fkan_gemm13(const float* __restrict__ x,
                                                      const short* __restrict__ Wb,
                                                      short* __restrict__ P) {
    // A: [128 rows][40 shorts] (80B stride; row*20 mod 32 bank starts =>
    //    balanced reads/writes, measured conflict-free in R9).
    // B: pair-row layout — LDS line l (128B, 8 slots) holds o-rows {2l,2l+1};
    //    logical chunk cb = (row&1)*4 + kchunk at slot cb ^ (l&7) (rule 21).
    __shared__ short As[2][128 * 40];   // 2 x 10 KB
    __shared__ short Bs[2][128 * 64];   // 2 x 16 KB

    const int bid = blockIdx.x;
    const int xcd = bid & 7;
    const int bn = xcd & 1, kc = xcd >> 1;          // 8 (bn,kc) combos -> 8 XCDs
    const int bm = bid >> 3;                        // [0,64)
    const int n0 = bm * 128, o0 = bn * 256, i0 = kc * 128;
    const int kbase = i0 * 16;
    const int NKT = 64;                             // 128 i / 2 i-per-kt

    const int tid = threadIdx.x;
    const int wid = tid >> 6, lane = tid & 63;
    const int l32 = lane & 31, hi32 = lane >> 5;
    const int wr = wid >> 1, wc = wid & 1;          // 2 x 2 wave grid

    f32x16 acc[2][4];                               // [mt][nt], 128 f32
#pragma unroll
    for (int a = 0; a < 2; ++a)
#pragma unroll
        for (int b = 0; b < 4; ++b)
#pragma unroll
            for (int e = 0; e < 16; ++e) acc[a][b][e] = 0.f;

    // A staging: 2 threads/row; thread -> row nl, x value i = i0 + kt*2 + isel
    const int nl = tid >> 1, isel = tid & 1;
    const float* xrow = x + (size_t)(n0 + nl) * 512 + i0 + isel;
    const int sAo = nl * 40 + isel * 16;            // shorts; +8 for hi chunk

    auto stage = [&](int t, int nb, float xx) {
        // ---- B: 16KB = 1024 x 16B chunks, 4 gload_lds per thread (rule 21)
#pragma unroll
        for (int w = 0; w < 4; ++w) {
            const int ch = w * 256 + tid;           // physical chunk index
            const int l = ch >> 3, sl = ch & 7;
            const int cb = sl ^ (l & 7);            // logical chunk at this slot
            const int r = 2 * l + (cb >> 2);        // o-row
            const short* src = Wb + (size_t)(o0 + r) * KDIM + kbase + t * 32 + (cb & 3) * 8;
            short* ldst = &Bs[nb][w * 2048 + wid * 512];  // wave-uniform base
            __builtin_amdgcn_global_load_lds(
                (const __attribute__((address_space(1))) void*)src,
                (__attribute__((address_space(3))) void*)ldst, 16, 0, 0);
        }
        // ---- A: 1 sincos + 8-harmonic recurrence -> 2 adjacent 16B chunks
        float s1, c1;
        __sincosf(xx, &s1, &c1);
        float c = c1, s = s1;
        i32x4 lo, hi;
#pragma unroll
        for (int g = 0; g < 8; ++g) {
            const int p = pkbf(c, s);
            if (g < 4) lo[g] = p; else hi[g - 4] = p;
            const float t1 = s * s1, t2 = c * s1;
            const float cn = __builtin_fmaf(c, c1, -t1);
            s = __builtin_fmaf(s, c1, t2);
            c = cn;
        }
        short* Ab = As[nb];
        *(i32x4*)&Ab[sAo]     = lo;                 // chunk isel*2
        *(i32x4*)&Ab[sAo + 8] = hi;                 // chunk isel*2+1
    };

    float xv = xrow[0];                 // kt = 0
    stage(0, 0, xv);
    xv = xrow[2];                       // kt = 1
    __syncthreads();

    for (int kt = 0; kt < NKT; ++kt) {
        const int cur = kt & 1;

        // ---- fragment reads: A row = wr*64+mt*32+l32, chunk = ks*2+hi32
        s16x8 af[2][2], bfr[4][2];      // [mt][ks], [nt][ks]
#pragma unroll
        for (int mt = 0; mt < 2; ++mt)
#pragma unroll
            for (int ks = 0; ks < 2; ++ks) {
                const int row = wr * 64 + mt * 32 + l32;
                af[mt][ks] = *(const s16x8*)&As[cur][row * 40 + (ks * 2 + hi32) * 8];
            }
#pragma unroll
        for (int nt = 0; nt < 4; ++nt)
#pragma unroll
            for (int ks = 0; ks < 2; ++ks) {
                const int row = wc * 128 + nt * 32 + l32;
                const int l = row >> 1;
                const int slot = (((row & 1) * 4 + ks * 2 + hi32) ^ (l & 7));
                bfr[nt][ks] = *(const s16x8*)&Bs[cur][l * 64 + slot * 8];
            }

        // ---- stage next tile into the other buffer (overlaps with MFMA)
        if (kt + 1 < NKT) {
            stage(kt + 1, cur ^ 1, xv);
            if (kt + 2 < NKT) xv = xrow[(kt + 2) * 2];
        }

        // ---- MFMA: 16 x 32x32x16 per wave per kt
#pragma unroll
        for (int ks = 0; ks < 2; ++ks)
#pragma unroll
            for (int mt = 0; mt < 2; ++mt)
#pragma unroll
                for (int nt = 0; nt < 4; ++nt)
                    acc[mt][nt] = __builtin_amdgcn_mfma_f32_32x32x16_bf16(
                        af[mt][ks], bfr[nt][ks], acc[mt][nt], 0, 0, 0);

        __syncthreads();
    }

    // ---- epilogue: bf16 partial. 32x32 D layout: col = lane&31,
    //      row = (reg&3) + 8*(reg>>2) + 4*(lane>>5)   [m74/m101]
    unsigned short* dst = (unsigned short*)P + (size_t)kc * (NROWS * ODIM);
#pragma unroll
    for (int mt = 0; mt < 2; ++mt)
#pragma unroll
        for (int nt = 0; nt < 4; ++nt) {
            const f32x16 v = acc[mt][nt];
            const int oc = o0 + wc * 128 + nt * 32 + l32;
            const int rb = n0 + wr * 64 + mt * 32 + 4 * hi32;
#pragma unroll
            for (int reg = 0; reg < 16; ++reg) {
                const int row = rb + (reg & 3) + 8 * (reg >> 2);
                dst[(size_t)row * 512 + oc] = (unsigned short)f2bf(v[reg]);
            }
        }
}

// ---- combine: out = sum_{q<4} f32(Pq) + bias ----
__global__ __launch_bounds__(256) void fkan_combine4(const short* __restrict__ P,
                                                     const float* __restrict__ bias,
                                                     float* __restrict__ out) {
    const int total = NROWS * ODIM;
    const int stride = gridDim.x * 256 * 8;
    for (int e = (blockIdx.x * 256 + threadIdx.x) * 8; e < total; e += stride) {
        s16x8 a = *(const s16x8*)(P + e);
        s16x8 b = *(const s16x8*)(P + total + e);
        s16x8 c = *(const s16x8*)(P + 2 * total + e);
        s16x8 d = *(const s16x8*)(P + 3 * total + e);
        const int col = e & 511;
        float4 c0 = *(const float4*)(bias + col);
        float4 c1 = *(const float4*)(bias + col + 4);
        float4 r0, r1;
        r0.x = (bf2f(a[0]) + bf2f(b[0])) + (bf2f(c[0]) + bf2f(d[0])) + c0.x;
        r0.y = (bf2f(a[1]) + bf2f(b[1])) + (bf2f(c[1]) + bf2f(d[1])) + c0.y;
        r0.z = (bf2f(a[2]) + bf2f(b[2])) + (bf2f(c[2]) + bf2f(d[2])) + c0.z;
        r0.w = (bf2f(a[3]) + bf2f(b[3])) + (bf2f(c[3]) + bf2f(d[3])) + c0.w;
        r1.x = (bf2f(a[4]) + bf2f(b[4])) + (bf2f(c[4]) + bf2f(d[4])) + c1.x;
        r1.y = (bf2f(a[5]) + bf2f(b[5])) + (bf2f(c[5]) + bf2f(d[5])) + c1.y;
        r1.z = (bf2f(a[6]) + bf2f(b[6])) + (bf2f(c[6]) + bf2f(d[6])) + c1.z;
        r1.w = (bf2f(a[7]) + bf2f(b[7])) + (bf2f(c[7]) + bf2f(d[7])) + c1.w;
        *(float4*)(out + e)     = r0;
        *(float4*)(out + e + 4) = r1;
    }
}

// ---- fallback (small ws): KSPLIT=1 structure, grid 256, f32 out + bias ----
__global__ __launch_bounds__(256, 2) void fkan_gemm_fb(const float* __restrict__ x,
                                                       const short* __restrict__ Wb,
                                                       const float* __restrict__ bias,
                                                       float* __restrict__ outp) {
    __shared__ short As[2][128 * 64];
    __shared__ short Bs[2][128 * 64];
    const int bid = blockIdx.x;
    const int xcd = bid & 7, idx = bid >> 3;
    const int bn = xcd & 3, bm = idx + (xcd >> 2) * 32;
    const int n0 = bm * 128, o0 = bn * 128;
    const int tid = threadIdx.x;
    const int wid = tid >> 6, lane = tid & 63;
    const int lrow = lane & 15, lk = lane >> 4;
    const int wr = wid >> 1, wc = wid & 1;
    f32x4 acc[4][4];
#pragma unroll
    for (int a = 0; a < 4; ++a)
#pragma unroll
        for (int b = 0; b < 4; ++b) { f32x4 z = {0,0,0,0}; acc[a][b] = z; }
    const int nl = tid >> 1, isel = tid & 1;
    const float* xrow = x + (n0 + nl) * 512 + isel * 2;
    auto stage = [&](int t, int nb, float2 xvv) {
#pragma unroll
        for (int w = 0; w < 4; ++w) {
            const int chunk = w * 256 + tid;
            const int r = chunk >> 3, pc = chunk & 7;
            const int lc = pc ^ (r & 7);
            const short* src = Wb + (o0 + r) * KDIM + t * 64 + lc * 8;
            short* ldst = &Bs[nb][w * 2048 + wid * 512];
            __builtin_amdgcn_global_load_lds(
                (const __attribute__((address_space(1))) void*)src,
                (__attribute__((address_space(3))) void*)ldst, 16, 0, 0);
        }
#pragma unroll
        for (int ii = 0; ii < 2; ++ii) {
            const float xx = ii ? xvv.y : xvv.x;
            float s1, c1; __sincosf(xx, &s1, &c1);
            float c = c1, s = s1;
            i32x4 lo, hi;
#pragma unroll
            for (int g = 0; g < 8; ++g) {
                const int p = pkbf(c, s);
                if (g < 4) lo[g] = p; else hi[g - 4] = p;
                const float t1 = s * s1, t2 = c * s1;
                const float cn = __builtin_fmaf(c, c1, -t1);
                s = __builtin_fmaf(s, c1, t2); c = cn;
            }
            const int cb0 = (isel * 2 + ii) * 2;
            *(i32x4*)&As[nb][nl * 64 + ((cb0 ^ (nl & 7))) * 8]       = lo;
            *(i32x4*)&As[nb][nl * 64 + (((cb0 + 1) ^ (nl & 7))) * 8] = hi;
        }
    };
    float2 xv = *(const float2*)xrow;
    stage(0, 0, xv);
    xv = *(const float2*)(xrow + 4);
    __syncthreads();
    for (int kt = 0; kt < 128; ++kt) {
        const int cur = kt & 1;
        s16x8 af[2][4], bfr[2][4];
#pragma unroll
        for (int ksub = 0; ksub < 2; ++ksub) {
#pragma unroll
            for (int mf = 0; mf < 4; ++mf) {
                const int row = wr * 64 + mf * 16 + lrow;
                af[ksub][mf] = *(const s16x8*)&As[cur][row * 64 + ((ksub * 4 + lk) ^ (row & 7)) * 8];
            }
#pragma unroll
            for (int nf = 0; nf < 4; ++nf) {
                const int row = wc * 64 + nf * 16 + lrow;
                bfr[ksub][nf] = *(const s16x8*)&Bs[cur][row * 64 + ((ksub * 4 + lk) ^ (row & 7)) * 8];
            }
        }
        if (kt + 1 < 128) {
            stage(kt + 1, cur ^ 1, xv);
            if (kt + 2 < 128) xv = *(const float2*)(xrow + (kt + 2) * 4);
        }
#pragma unroll
        for (int ksub = 0; ksub < 2; ++ksub)
#pragma unroll
            for (int mf = 0; mf < 4; ++mf)
#pragma unroll
                for (int nf = 0; nf < 4; ++nf)
                    acc[mf][nf] = __builtin_amdgcn_mfma_f32_16x16x32_bf16(
                        af[ksub][mf], bfr[ksub][nf], acc[mf][nf], 0, 0, 0);
        __syncthreads();
    }
#pragma unroll
    for (int nf = 0; nf < 4; ++nf) {
        const int oc = o0 + wc * 64 + nf * 16 + lrow;
        const float bv = bias[oc];
#pragma unroll
        for (int mf = 0; mf < 4; ++mf) {
            const f32x4 v = acc[mf][nf];
            const int rbase = n0 + wr * 64 + mf * 16 + lk * 4;
#pragma unroll
            for (int j = 0; j < 4; ++j)
                outp[(size_t)(rbase + j) * 512 + oc] = v[j] + bv;
        }
    }
}

extern "C" void kernel_launch(void* const* d_in, const int* in_sizes, int n_in,
                              void* d_out, int out_size, void* d_ws, size_t ws_size,
                              hipStream_t stream) {
    const float* x    = (const float*)d_in[0];
    const float* cf   = (const float*)d_in[1];
    const float* bias = (const float*)d_in[2];
    float* out = (float*)d_out;

    const size_t partial_bytes = (size_t)4 * NROWS * ODIM * 2;   // 33.6 MB (bf16 x4)
    const size_t wb_bytes = (size_t)ODIM * KDIM * 2;             // 8.4 MB

    if (ws_size >= partial_bytes + wb_bytes) {
        short* P  = (short*)d_ws;
        short* Wb = (short*)((char*)d_ws + partial_bytes);
        fkan_prep<<<512, 256, 0, stream>>>(cf, Wb);
        fkan_gemm13<<<512, 256, 0, stream>>>(x, Wb, P);
        fkan_combine4<<<2048, 256, 0, stream>>>(P, bias, out);
    } else {
        short* Wb = (short*)d_ws;
        fkan_prep<<<512, 256, 0, stream>>>(cf, Wb);
        fkan_gemm_fb<<<256, 256, 0, stream>>>(x, Wb, bias, out);
    }
}

// Round 14
// 90.213 us; speedup vs baseline: 1.3779x; 1.0756x over previous
//
#include <hip/hip_runtime.h>
#include <hip/hip_bf16.h>

// FourierKANLayer: y[n,o] = sum_{i,g} cos(x[n,i]*(g+1))*C[0,o,i,g]
//                         + sin(x[n,i]*(g+1))*C[1,o,i,g] + bias[o]
// N=8192, I=512, O=512, G=8  ->  GEMM [N x K]*[K x O], K = I*16 = 8192
// Round 14: 256x256 tile, 1 block/CU. Corrected pipe model showed ~50% of
// the wall is per-wave critical-path dead time (read latency + 512-cyc MFMA
// issue + barrier) at 16 MFMA/wave-kt. Quadrupling MFMA per barrier interval
// (wave tile 128x128 -> 32 MFMA = 1024 issue-cyc) amortizes the fixed
// latency+barrier cost; LDS ops per MFMA halve. acc 256 VGPR, 1 wave/SIMD.

typedef __attribute__((ext_vector_type(8)))  short s16x8;
typedef __attribute__((ext_vector_type(4)))  int   i32x4;
typedef __attribute__((ext_vector_type(4)))  float f32x4;
typedef __attribute__((ext_vector_type(16))) float f32x16;

#define NROWS 8192
#define IDIM  512
#define ODIM  512
#define KDIM  8192   // IDIM*16

static __device__ __forceinline__ short f2bf(float f) {
    union { float f; unsigned u; } v; v.f = f;
    unsigned r = v.u + 0x7fffu + ((v.u >> 16) & 1u);  // RNE
    return (short)(r >> 16);
}

static __device__ __forceinline__ float bf2f(short h) {
    union { unsigned u; float f; } v;
    v.u = ((unsigned)(unsigned short)h) << 16;
    return v.f;
}

static __device__ __forceinline__ int pkbf(float c, float s) {
    union { __hip_bfloat162 h; int i; } u;
    u.h = __float22bfloat162_rn(make_float2(c, s));   // low = cos, high = sin
    return u.i;
}

// ---- prep: coeffs [2][O][I][G] f32  ->  Wb[O][K] bf16, k = i*16 + 2g + t ----
__global__ __launch_bounds__(256) void fkan_prep(const float* __restrict__ cf,
                                                 short* __restrict__ Wb) {
    const int o = blockIdx.x;
    const int tid = threadIdx.x;
#pragma unroll
    for (int rep = 0; rep < 2; ++rep) {
        const int i = tid + rep * 256;
        const float* c0 = cf + (o * 512 + i) * 8;            // t=0
        const float* c1 = cf + ((512 + o) * 512 + i) * 8;    // t=1
        float4 a0 = *(const float4*)c0;
        float4 a1 = *(const float4*)(c0 + 4);
        float4 b0 = *(const float4*)c1;
        float4 b1 = *(const float4*)(c1 + 4);
        s16x8 lo, hi;
        lo[0] = f2bf(a0.x); lo[1] = f2bf(b0.x);
        lo[2] = f2bf(a0.y); lo[3] = f2bf(b0.y);
        lo[4] = f2bf(a0.z); lo[5] = f2bf(b0.z);
        lo[6] = f2bf(a0.w); lo[7] = f2bf(b0.w);
        hi[0] = f2bf(a1.x); hi[1] = f2bf(b1.x);
        hi[2] = f2bf(a1.y); hi[3] = f2bf(b1.y);
        hi[4] = f2bf(a1.z); hi[5] = f2bf(b1.z);
        hi[6] = f2bf(a1.w); hi[7] = f2bf(b1.w);
        *(s16x8*)(Wb + o * KDIM + i * 16)     = lo;
        *(s16x8*)(Wb + o * KDIM + i * 16 + 8) = hi;
    }
}

// ---- main GEMM: BM=256, BN=256, BK=32, 256 threads (4 waves, 2x2) ----
// grid 256 (32 bm x 2 bn x 4 kc), 1 block/CU. Wave tile 128x128, 32x32x16.
__global__ __launch_bounds__(256, 1) void fkan_gemm14(const float* __restrict__ x,
                                                      const short* __restrict__ Wb,
                                                      short* __restrict__ P) {
    // A: [256 rows][40 shorts] (80B stride, bank-balanced — R9/R13 proven).
    // B: pair-row — LDS line l (128B, 8 slots) holds o-rows {2l,2l+1};
    //    logical chunk cb = (row&1)*4 + kchunk at slot cb ^ (l&7) (rule 21).
    __shared__ short As[2][256 * 40];   // 2 x 20 KB
    __shared__ short Bs[2][128 * 64];   // 2 x 16 KB

    const int bid = blockIdx.x;
    const int xcd = bid & 7;
    const int bn = xcd & 1, kc = xcd >> 1;          // 8 (bn,kc) combos -> 8 XCDs
    const int bm = bid >> 3;                        // [0,32)
    const int n0 = bm * 256, o0 = bn * 256, i0 = kc * 128;
    const int kbase = i0 * 16;
    const int NKT = 64;                             // 128 i / 2 i-per-kt

    const int tid = threadIdx.x;
    const int wid = tid >> 6, lane = tid & 63;
    const int l32 = lane & 31, hi32 = lane >> 5;
    const int wr = wid >> 1, wc = wid & 1;          // 2 x 2 wave grid

    f32x16 acc[4][4];                               // [mt][nt], 256 f32
#pragma unroll
    for (int a = 0; a < 4; ++a)
#pragma unroll
        for (int b = 0; b < 4; ++b)
#pragma unroll
            for (int e = 0; e < 16; ++e) acc[a][b][e] = 0.f;

    // A staging: thread t -> row t, BOTH i values of the kt (float2, L1-friendly)
    const float* xrow = x + (size_t)(n0 + tid) * 512 + i0;
    const int sAo = tid * 40;                       // shorts

    auto stage = [&](int t, int nb, float2 xv) {
        // ---- B: 16KB = 1024 x 16B chunks, 4 gload_lds per thread (rule 21)
#pragma unroll
        for (int w = 0; w < 4; ++w) {
            const int ch = w * 256 + tid;           // physical chunk index
            const int l = ch >> 3, sl = ch & 7;
            const int cb = sl ^ (l & 7);            // logical chunk at this slot
            const int r = 2 * l + (cb >> 2);        // o-row
            const short* src = Wb + (size_t)(o0 + r) * KDIM + kbase + t * 32 + (cb & 3) * 8;
            short* ldst = &Bs[nb][w * 2048 + wid * 512];  // wave-uniform base
            __builtin_amdgcn_global_load_lds(
                (const __attribute__((address_space(1))) void*)src,
                (__attribute__((address_space(3))) void*)ldst, 16, 0, 0);
        }
        // ---- A: 2 sincos (both i of this kt) -> 4 adjacent 16B chunks
        short* Ab = As[nb];
#pragma unroll
        for (int ii = 0; ii < 2; ++ii) {
            const float xx = ii ? xv.y : xv.x;
            float s1, c1;
            __sincosf(xx, &s1, &c1);
            float c = c1, s = s1;
            i32x4 lo, hi;
#pragma unroll
            for (int g = 0; g < 8; ++g) {
                const int p = pkbf(c, s);
                if (g < 4) lo[g] = p; else hi[g - 4] = p;
                const float t1 = s * s1, t2 = c * s1;
                const float cn = __builtin_fmaf(c, c1, -t1);
                s = __builtin_fmaf(s, c1, t2);
                c = cn;
            }
            *(i32x4*)&Ab[sAo + ii * 16]     = lo;   // chunk ii*2
            *(i32x4*)&Ab[sAo + ii * 16 + 8] = hi;   // chunk ii*2+1
        }
    };

    float2 xv = *(const float2*)xrow;               // kt = 0
    stage(0, 0, xv);
    xv = *(const float2*)(xrow + 2);                // kt = 1
    __syncthreads();

    for (int kt = 0; kt < NKT; ++kt) {
        const int cur = kt & 1;

        // ---- fragment reads: A row = wr*128+mt*32+l32, chunk ks*2+hi32
        s16x8 af[4][2], bfr[4][2];      // [mt][ks], [nt][ks]
#pragma unroll
        for (int mt = 0; mt < 4; ++mt)
#pragma unroll
            for (int ks = 0; ks < 2; ++ks) {
                const int row = wr * 128 + mt * 32 + l32;
                af[mt][ks] = *(const s16x8*)&As[cur][row * 40 + (ks * 2 + hi32) * 8];
            }
#pragma unroll
        for (int nt = 0; nt < 4; ++nt)
#pragma unroll
            for (int ks = 0; ks < 2; ++ks) {
                const int row = wc * 128 + nt * 32 + l32;
                const int l = row >> 1;
                const int slot = (((row & 1) * 4 + ks * 2 + hi32) ^ (l & 7));
                bfr[nt][ks] = *(const s16x8*)&Bs[cur][l * 64 + slot * 8];
            }

        // ---- stage next tile into the other buffer (overlaps with MFMA)
        if (kt + 1 < NKT) {
            stage(kt + 1, cur ^ 1, xv);
            if (kt + 2 < NKT) xv = *(const float2*)(xrow + (kt + 2) * 2);
        }

        // ---- MFMA: 32 x 32x32x16 per wave per kt (1024 issue-cyc/SIMD)
#pragma unroll
        for (int ks = 0; ks < 2; ++ks)
#pragma unroll
            for (int mt = 0; mt < 4; ++mt)
#pragma unroll
                for (int nt = 0; nt < 4; ++nt)
                    acc[mt][nt] = __builtin_amdgcn_mfma_f32_32x32x16_bf16(
                        af[mt][ks], bfr[nt][ks], acc[mt][nt], 0, 0, 0);

        __syncthreads();
    }

    // ---- epilogue: bf16 partial. 32x32 D layout: col = lane&31,
    //      row = (reg&3) + 8*(reg>>2) + 4*(lane>>5)   [m74/m101]
    unsigned short* dst = (unsigned short*)P + (size_t)kc * (NROWS * ODIM);
#pragma unroll
    for (int mt = 0; mt < 4; ++mt)
#pragma unroll
        for (int nt = 0; nt < 4; ++nt) {
            const f32x16 v = acc[mt][nt];
            const int oc = o0 + wc * 128 + nt * 32 + l32;
            const int rb = n0 + wr * 128 + mt * 32 + 4 * hi32;
#pragma unroll
            for (int reg = 0; reg < 16; ++reg) {
                const int row = rb + (reg & 3) + 8 * (reg >> 2);
                dst[(size_t)row * 512 + oc] = (unsigned short)f2bf(v[reg]);
            }
        }
}

// ---- combine: out = sum_{q<4} f32(Pq) + bias ----
__global__ __launch_bounds__(256) void fkan_combine4(const short* __restrict__ P,
                                                     const float* __restrict__ bias,
                                                     float* __restrict__ out) {
    const int total = NROWS * ODIM;
    const int stride = gridDim.x * 256 * 8;
    for (int e = (blockIdx.x * 256 + threadIdx.x) * 8; e < total; e += stride) {
        s16x8 a = *(const s16x8*)(P + e);
        s16x8 b = *(const s16x8*)(P + total + e);
        s16x8 c = *(const s16x8*)(P + 2 * total + e);
        s16x8 d = *(const s16x8*)(P + 3 * total + e);
        const int col = e & 511;
        float4 c0 = *(const float4*)(bias + col);
        float4 c1 = *(const float4*)(bias + col + 4);
        float4 r0, r1;
        r0.x = (bf2f(a[0]) + bf2f(b[0])) + (bf2f(c[0]) + bf2f(d[0])) + c0.x;
        r0.y = (bf2f(a[1]) + bf2f(b[1])) + (bf2f(c[1]) + bf2f(d[1])) + c0.y;
        r0.z = (bf2f(a[2]) + bf2f(b[2])) + (bf2f(c[2]) + bf2f(d[2])) + c0.z;
        r0.w = (bf2f(a[3]) + bf2f(b[3])) + (bf2f(c[3]) + bf2f(d[3])) + c0.w;
        r1.x = (bf2f(a[4]) + bf2f(b[4])) + (bf2f(c[4]) + bf2f(d[4])) + c1.x;
        r1.y = (bf2f(a[5]) + bf2f(b[5])) + (bf2f(c[5]) + bf2f(d[5])) + c1.y;
        r1.z = (bf2f(a[6]) + bf2f(b[6])) + (bf2f(c[6]) + bf2f(d[6])) + c1.z;
        r1.w = (bf2f(a[7]) + bf2f(b[7])) + (bf2f(c[7]) + bf2f(d[7])) + c1.w;
        *(float4*)(out + e)     = r0;
        *(float4*)(out + e + 4) = r1;
    }
}

// ---- fallback (small ws): KSPLIT=1 structure, grid 256, f32 out + bias ----
__global__ __launch_bounds__(256, 2) void fkan_gemm_fb(const float* __restrict__ x,
                                                       const short* __restrict__ Wb,
                                                       const float* __restrict__ bias,
                                                       float* __restrict__ outp) {
    __shared__ short As[2][128 * 64];
    __shared__ short Bs[2][128 * 64];
    const int bid = blockIdx.x;
    const int xcd = bid & 7, idx = bid >> 3;
    const int bn = xcd & 3, bm = idx + (xcd >> 2) * 32;
    const int n0 = bm * 128, o0 = bn * 128;
    const int tid = threadIdx.x;
    const int wid = tid >> 6, lane = tid & 63;
    const int lrow = lane & 15, lk = lane >> 4;
    const int wr = wid >> 1, wc = wid & 1;
    f32x4 acc[4][4];
#pragma unroll
    for (int a = 0; a < 4; ++a)
#pragma unroll
        for (int b = 0; b < 4; ++b) { f32x4 z = {0,0,0,0}; acc[a][b] = z; }
    const int nl = tid >> 1, isel = tid & 1;
    const float* xrow = x + (n0 + nl) * 512 + isel * 2;
    auto stage = [&](int t, int nb, float2 xvv) {
#pragma unroll
        for (int w = 0; w < 4; ++w) {
            const int chunk = w * 256 + tid;
            const int r = chunk >> 3, pc = chunk & 7;
            const int lc = pc ^ (r & 7);
            const short* src = Wb + (o0 + r) * KDIM + t * 64 + lc * 8;
            short* ldst = &Bs[nb][w * 2048 + wid * 512];
            __builtin_amdgcn_global_load_lds(
                (const __attribute__((address_space(1))) void*)src,
                (__attribute__((address_space(3))) void*)ldst, 16, 0, 0);
        }
#pragma unroll
        for (int ii = 0; ii < 2; ++ii) {
            const float xx = ii ? xvv.y : xvv.x;
            float s1, c1; __sincosf(xx, &s1, &c1);
            float c = c1, s = s1;
            i32x4 lo, hi;
#pragma unroll
            for (int g = 0; g < 8; ++g) {
                const int p = pkbf(c, s);
                if (g < 4) lo[g] = p; else hi[g - 4] = p;
                const float t1 = s * s1, t2 = c * s1;
                const float cn = __builtin_fmaf(c, c1, -t1);
                s = __builtin_fmaf(s, c1, t2); c = cn;
            }
            const int cb0 = (isel * 2 + ii) * 2;
            *(i32x4*)&As[nb][nl * 64 + ((cb0 ^ (nl & 7))) * 8]       = lo;
            *(i32x4*)&As[nb][nl * 64 + (((cb0 + 1) ^ (nl & 7))) * 8] = hi;
        }
    };
    float2 xv = *(const float2*)xrow;
    stage(0, 0, xv);
    xv = *(const float2*)(xrow + 4);
    __syncthreads();
    for (int kt = 0; kt < 128; ++kt) {
        const int cur = kt & 1;
        s16x8 af[2][4], bfr[2][4];
#pragma unroll
        for (int ksub = 0; ksub < 2; ++ksub) {
#pragma unroll
            for (int mf = 0; mf < 4; ++mf) {
                const int row = wr * 64 + mf * 16 + lrow;
                af[ksub][mf] = *(const s16x8*)&As[cur][row * 64 + ((ksub * 4 + lk) ^ (row & 7)) * 8];
            }
#pragma unroll
            for (int nf = 0; nf < 4; ++nf) {
                const int row = wc * 64 + nf * 16 + lrow;
                bfr[ksub][nf] = *(const s16x8*)&Bs[cur][row * 64 + ((ksub * 4 + lk) ^ (row & 7)) * 8];
            }
        }
        if (kt + 1 < 128) {
            stage(kt + 1, cur ^ 1, xv);
            if (kt + 2 < 128) xv = *(const float2*)(xrow + (kt + 2) * 4);
        }
#pragma unroll
        for (int ksub = 0; ksub < 2; ++ksub)
#pragma unroll
            for (int mf = 0; mf < 4; ++mf)
#pragma unroll
                for (int nf = 0; nf < 4; ++nf)
                    acc[mf][nf] = __builtin_amdgcn_mfma_f32_16x16x32_bf16(
                        af[ksub][mf], bfr[ksub][nf], acc[mf][nf], 0, 0, 0);
        __syncthreads();
    }
#pragma unroll
    for (int nf = 0; nf < 4; ++nf) {
        const int oc = o0 + wc * 64 + nf * 16 + lrow;
        const float bv = bias[oc];
#pragma unroll
        for (int mf = 0; mf < 4; ++mf) {
            const f32x4 v = acc[mf][nf];
            const int rbase = n0 + wr * 64 + mf * 16 + lk * 4;
#pragma unroll
            for (int j = 0; j < 4; ++j)
                outp[(size_t)(rbase + j) * 512 + oc] = v[j] + bv;
        }
    }
}

extern "C" void kernel_launch(void* const* d_in, const int* in_sizes, int n_in,
                              void* d_out, int out_size, void* d_ws, size_t ws_size,
                              hipStream_t stream) {
    const float* x    = (const float*)d_in[0];
    const float* cf   = (const float*)d_in[1];
    const float* bias = (const float*)d_in[2];
    float* out = (float*)d_out;

    const size_t partial_bytes = (size_t)4 * NROWS * ODIM * 2;   // 33.6 MB (bf16 x4)
    const size_t wb_bytes = (size_t)ODIM * KDIM * 2;             // 8.4 MB

    if (ws_size >= partial_bytes + wb_bytes) {
        short* P  = (short*)d_ws;
        short* Wb = (short*)((char*)d_ws + partial_bytes);
        fkan_prep<<<512, 256, 0, stream>>>(cf, Wb);
        fkan_gemm14<<<256, 256, 0, stream>>>(x, Wb, P);
        fkan_combine4<<<2048, 256, 0, stream>>>(P, bias, out);
    } else {
        short* Wb = (short*)d_ws;
        fkan_prep<<<512, 256, 0, stream>>>(cf, Wb);
        fkan_gemm_fb<<<256, 256, 0, stream>>>(x, Wb, bias, out);
    }
}